// Round 2
// baseline (61280.579 us; speedup 1.0000x reference)
//
#include <hip/hip_runtime.h>
#include <stdint.h>

#define BB 128      // batch
#define TT 150      // seq len
#define HH 512      // hidden
#define AA 512      // attention dim
#define SS 1024     // 2A (softmax length)
#define VV 600      // vocab / output size
#define KCAT 1112   // V + H
#define G3 1536     // 3H
#define NB 256      // persistent grid (1 block/CU, co-resident)
#define TPB 512     // 8 waves

typedef short s8v __attribute__((ext_vector_type(8)));   // 8 x bf16
typedef float f4v __attribute__((ext_vector_type(4)));   // 4 x f32 acc

__device__ __forceinline__ ushort f2bf(float f) {
    uint32_t u = __builtin_bit_cast(uint32_t, f);
    uint32_t r = (u + 0x7fffu + ((u >> 16) & 1u)) >> 16;  // RNE
    return (ushort)r;
}
__device__ __forceinline__ float bflo(uint32_t x) {
    uint32_t u = (x & 0xffffu) << 16;
    return __builtin_bit_cast(float, u);
}
__device__ __forceinline__ float bfhi(uint32_t x) {
    uint32_t u = x & 0xffff0000u;
    return __builtin_bit_cast(float, u);
}

// ---------------- conversion: fp32 -> bf16 ----------------
__global__ void k_cvt4(const float4* __restrict__ src, ushort* __restrict__ dst, long n4) {
    long i = (long)blockIdx.x * blockDim.x + threadIdx.x;
    long st = (long)gridDim.x * blockDim.x;
    for (; i < n4; i += st) {
        float4 v = src[i];
        ushort4 o;
        o.x = f2bf(v.x); o.y = f2bf(v.y); o.z = f2bf(v.z); o.w = f2bf(v.w);
        *(ushort4*)(dst + i * 4) = o;
    }
}

__global__ void k_init_h(const float* __restrict__ hidden, float* __restrict__ hf,
                         ushort* __restrict__ hb) {
    int i = blockIdx.x * 256 + threadIdx.x;   // grid 256 -> 65536
    float v = hidden[i];
    hf[i] = v;
    hb[i] = f2bf(v);
}

struct Prm {
    const ushort* tseqb; const ushort* encb; const float* encf;
    const ushort *Wab, *Wcb, *Wihb, *Whhb, *Wob;
    const float *ba, *bc, *bih, *bhh, *bo;
    float *lp0, *lp1, *ghb, *part;
    float *hf0, *hf1; ushort *hb0, *hb1; ushort *gruin;
    float *out;
    int *cnt; int *gen;
};

// grid barrier: agent-scope atomics (release via cnt add, acquire via gen spin)
__device__ __forceinline__ void gbar(int* cnt, int* gen) {
    __syncthreads();
    if (threadIdx.x == 0) {
        int g = __hip_atomic_load(gen, __ATOMIC_RELAXED, __HIP_MEMORY_SCOPE_AGENT);
        int v = __hip_atomic_fetch_add(cnt, 1, __ATOMIC_ACQ_REL, __HIP_MEMORY_SCOPE_AGENT);
        if (v == NB - 1) {
            __hip_atomic_store(cnt, 0, __ATOMIC_RELAXED, __HIP_MEMORY_SCOPE_AGENT);
            __hip_atomic_fetch_add(gen, 1, __ATOMIC_ACQ_REL, __HIP_MEMORY_SCOPE_AGENT);
        } else {
            int it = 0;
            while (__hip_atomic_load(gen, __ATOMIC_ACQUIRE, __HIP_MEMORY_SCOPE_AGENT) == g) {
                __builtin_amdgcn_s_sleep(2);
                if (++it > (1 << 26)) break;   // safety valve: no infinite hang
            }
        }
    }
    __syncthreads();
}

__device__ __forceinline__ s8v ldA(const ushort* tseqb, const ushort* hb,
                                   int row, int kb, int t) {
    const s8v zf = {0, 0, 0, 0, 0, 0, 0, 0};
    if (kb >= KCAT) return zf;
    if (kb < VV) {
        if (t == 0) return zf;
        return *(const s8v*)(tseqb + ((size_t)row * TT + (t - 1)) * VV + kb);
    }
    return *(const s8v*)(hb + row * HH + (kb - VV));
}

template <int EBF>
__global__ __launch_bounds__(TPB, 2) void kper(Prm p) {
    const int bid = blockIdx.x;
    const int tid = threadIdx.x;
    const int wave = tid >> 6, lane = tid & 63;
    const int l15 = lane & 15, lg = lane >> 4;
    const s8v zf = {0, 0, 0, 0, 0, 0, 0, 0};
    __shared__ float aw[SS];
    __shared__ float red[TPB];
    __shared__ float redc[8][AA];

    for (int t = 0; t < TT; ++t) {
        const float*  hfc = (t & 1) ? p.hf1 : p.hf0;
        const ushort* hbc = (t & 1) ? p.hb1 : p.hb0;
        float*  hfn = (t & 1) ? p.hf0 : p.hf1;
        ushort* hbn = (t & 1) ? p.hb0 : p.hb1;

        // ======== phase A: logits split-K (no bias) + gh ========
        if (bid < 64) {
            const int ks = bid & 1, nt = bid >> 1;
            const int n0 = nt * 32;
            const int row = wave * 16 + l15;
            const int kc0 = ks ? 18 : 0, kc1 = ks ? 35 : 18;
            f4v acc[2] = {};
            for (int kc = kc0; kc < kc1; ++kc) {
                const int kb = kc * 32 + lg * 8;
                s8v a = ldA(p.tseqb, hbc, row, kb, t);
#pragma unroll
                for (int q = 0; q < 2; ++q) {
                    const int n = n0 + q * 16 + l15;
                    s8v b = (kb < KCAT) ? *(const s8v*)(p.Wab + (size_t)n * KCAT + kb) : zf;
                    acc[q] = __builtin_amdgcn_mfma_f32_16x16x32_bf16(a, b, acc[q], 0, 0, 0);
                }
            }
            float* lp = ks ? p.lp1 : p.lp0;
#pragma unroll
            for (int q = 0; q < 2; ++q) {
                const int n = n0 + q * 16 + l15;
#pragma unroll
                for (int i = 0; i < 4; ++i) {
                    const int m = wave * 16 + lg * 4 + i;
                    lp[m * SS + n] = acc[q][i];
                }
            }
        } else if (bid < 112) {
            const int jt = bid - 64;
            const int n0 = jt * 32;
            const int row = wave * 16 + l15;
            f4v acc[2] = {};
            for (int kc = 0; kc < 16; ++kc) {
                const int kb = kc * 32 + lg * 8;
                s8v a = *(const s8v*)(hbc + row * HH + kb);
#pragma unroll
                for (int q = 0; q < 2; ++q) {
                    const int n = n0 + q * 16 + l15;
                    s8v b = *(const s8v*)(p.Whhb + (size_t)n * HH + kb);
                    acc[q] = __builtin_amdgcn_mfma_f32_16x16x32_bf16(a, b, acc[q], 0, 0, 0);
                }
            }
#pragma unroll
            for (int q = 0; q < 2; ++q) {
                const int n = n0 + q * 16 + l15;
                const float bias = p.bhh[n];
#pragma unroll
                for (int i = 0; i < 4; ++i) {
                    const int m = wave * 16 + lg * 4 + i;
                    p.ghb[m * G3 + n] = acc[q][i] + bias;
                }
            }
        }
        gbar(p.cnt, p.gen);

        // ======== phase B: softmax (redundant stats) + attention half-row ========
        {
            const int b = bid >> 1, half = bid & 1;
            const int s0 = tid * 2;
            float l0 = p.lp0[b * SS + s0]     + p.lp1[b * SS + s0]     + p.ba[s0];
            float l1 = p.lp0[b * SS + s0 + 1] + p.lp1[b * SS + s0 + 1] + p.ba[s0 + 1];
            red[tid] = fmaxf(l0, l1);
            __syncthreads();
            for (int s = TPB / 2; s > 0; s >>= 1) {
                if (tid < s) red[tid] = fmaxf(red[tid], red[tid + s]);
                __syncthreads();
            }
            const float mx = red[0];
            __syncthreads();
            float e0 = __expf(l0 - mx), e1 = __expf(l1 - mx);
            aw[s0] = e0; aw[s0 + 1] = e1;
            red[tid] = e0 + e1;
            __syncthreads();
            for (int s = TPB / 2; s > 0; s >>= 1) {
                if (tid < s) red[tid] += red[tid + s];
                __syncthreads();
            }
            const float inv = 1.0f / red[0];
            __syncthreads();

            float acc[8] = {0, 0, 0, 0, 0, 0, 0, 0};
            const int c0 = lane * 8;
#pragma unroll 4
            for (int it = 0; it < 64; ++it) {
                const int s = half * 512 + it * 8 + wave;
                const float w = aw[s];
                if (EBF) {
                    uint4 u = *(const uint4*)((const ushort*)p.encb + ((size_t)b * SS + s) * AA + c0);
                    acc[0] += w * bflo(u.x); acc[1] += w * bfhi(u.x);
                    acc[2] += w * bflo(u.y); acc[3] += w * bfhi(u.y);
                    acc[4] += w * bflo(u.z); acc[5] += w * bfhi(u.z);
                    acc[6] += w * bflo(u.w); acc[7] += w * bfhi(u.w);
                } else {
                    const float* rp = p.encf + ((size_t)b * SS + s) * AA + c0;
                    float4 v0 = *(const float4*)rp;
                    float4 v1 = *(const float4*)(rp + 4);
                    acc[0] += w * v0.x; acc[1] += w * v0.y;
                    acc[2] += w * v0.z; acc[3] += w * v0.w;
                    acc[4] += w * v1.x; acc[5] += w * v1.y;
                    acc[6] += w * v1.z; acc[7] += w * v1.w;
                }
            }
#pragma unroll
            for (int j = 0; j < 8; ++j) redc[wave][c0 + j] = acc[j];
            __syncthreads();
            {
                const int c = tid;  // 512 threads cover AA=512
                float s = ((redc[0][c] + redc[1][c]) + (redc[2][c] + redc[3][c]))
                        + ((redc[4][c] + redc[5][c]) + (redc[6][c] + redc[7][c]));
                p.part[((size_t)half * BB + b) * AA + c] = s * inv;
            }
        }
        gbar(p.cnt, p.gen);

        // ======== phase C: gru_in + out[t-1] ========
        if (bid < 16) {
            const int n0 = bid * 32;
            const int row = wave * 16 + l15;
            f4v acc[2] = {};
            for (int kc = 0; kc < 35; ++kc) {
                const int kb = kc * 32 + lg * 8;
                s8v a;
                if (kb >= KCAT) a = zf;
                else if (kb < VV) {
                    a = (t == 0) ? zf
                        : *(const s8v*)(p.tseqb + ((size_t)row * TT + (t - 1)) * VV + kb);
                } else {
                    const int ko = kb - VV;
                    const float* q0 = p.part + ((size_t)0 * BB + row) * AA + ko;
                    const float* q1 = p.part + ((size_t)1 * BB + row) * AA + ko;
                    float4 x0 = *(const float4*)q0, y0 = *(const float4*)(q0 + 4);
                    float4 x1 = *(const float4*)q1, y1 = *(const float4*)(q1 + 4);
                    union { s8v v; ushort u[8]; } tu;
                    tu.u[0] = f2bf(x0.x + x1.x); tu.u[1] = f2bf(x0.y + x1.y);
                    tu.u[2] = f2bf(x0.z + x1.z); tu.u[3] = f2bf(x0.w + x1.w);
                    tu.u[4] = f2bf(y0.x + y1.x); tu.u[5] = f2bf(y0.y + y1.y);
                    tu.u[6] = f2bf(y0.z + y1.z); tu.u[7] = f2bf(y0.w + y1.w);
                    a = tu.v;
                }
#pragma unroll
                for (int q = 0; q < 2; ++q) {
                    const int n = n0 + q * 16 + l15;
                    s8v b = (kb < KCAT) ? *(const s8v*)(p.Wcb + (size_t)n * KCAT + kb) : zf;
                    acc[q] = __builtin_amdgcn_mfma_f32_16x16x32_bf16(a, b, acc[q], 0, 0, 0);
                }
            }
#pragma unroll
            for (int q = 0; q < 2; ++q) {
                const int n = n0 + q * 16 + l15;
                const float bias = p.bc[n];
#pragma unroll
                for (int i = 0; i < 4; ++i) {
                    const int m = wave * 16 + lg * 4 + i;
                    float v = acc[q][i] + bias;
                    p.gruin[m * HH + n] = f2bf(v > 0.0f ? v : 0.0f);
                }
            }
        } else if (bid < 35 && t > 0) {
            const int nt = bid - 16;
            const int n0 = nt * 32;
            const int row = wave * 16 + l15;
            f4v acc[2] = {};
            for (int kc = 0; kc < 16; ++kc) {
                const int kb = kc * 32 + lg * 8;
                s8v a = *(const s8v*)(hbc + row * HH + kb);
#pragma unroll
                for (int q = 0; q < 2; ++q) {
                    int n = n0 + q * 16 + l15;
                    if (n >= VV) n = VV - 1;      // clamp load, mask store
                    s8v b = *(const s8v*)(p.Wob + (size_t)n * HH + kb);
                    acc[q] = __builtin_amdgcn_mfma_f32_16x16x32_bf16(a, b, acc[q], 0, 0, 0);
                }
            }
#pragma unroll
            for (int q = 0; q < 2; ++q) {
                const int n = n0 + q * 16 + l15;
                if (n < VV) {
                    const float bias = p.bo[n];
#pragma unroll
                    for (int i = 0; i < 4; ++i) {
                        const int m = wave * 16 + lg * 4 + i;
                        p.out[((size_t)m * TT + (t - 1)) * VV + n] = acc[q][i] + bias;
                    }
                }
            }
        }
        gbar(p.cnt, p.gen);

        // ======== phase D: gi + gates + h_new ========
        if (bid < 32) {
            const int j0 = bid * 16;
            const int row = wave * 16 + l15;
            const int n = j0 + l15;
            f4v ar = {}, az = {}, an = {};
            for (int kc = 0; kc < 16; ++kc) {
                const int kb = kc * 32 + lg * 8;
                s8v a  = *(const s8v*)(p.gruin + row * HH + kb);
                s8v br = *(const s8v*)(p.Wihb + (size_t)n * HH + kb);
                s8v bz = *(const s8v*)(p.Wihb + (size_t)(HH + n) * HH + kb);
                s8v bn = *(const s8v*)(p.Wihb + (size_t)(2 * HH + n) * HH + kb);
                ar = __builtin_amdgcn_mfma_f32_16x16x32_bf16(a, br, ar, 0, 0, 0);
                az = __builtin_amdgcn_mfma_f32_16x16x32_bf16(a, bz, az, 0, 0, 0);
                an = __builtin_amdgcn_mfma_f32_16x16x32_bf16(a, bn, an, 0, 0, 0);
            }
            const float br_ = p.bih[n], bz_ = p.bih[HH + n], bn_ = p.bih[2 * HH + n];
#pragma unroll
            for (int i = 0; i < 4; ++i) {
                const int m = wave * 16 + lg * 4 + i;
                const float* ghm = p.ghb + (size_t)m * G3;
                float gr = ar[i] + br_ + ghm[n];
                float gz = az[i] + bz_ + ghm[HH + n];
                float r = 1.0f / (1.0f + __expf(-gr));
                float z = 1.0f / (1.0f + __expf(-gz));
                float nn = tanhf(an[i] + bn_ + r * ghm[2 * HH + n]);
                float hold = hfc[m * HH + n];
                float hv = (1.0f - z) * nn + z * hold;
                hfn[m * HH + n] = hv;
                hbn[m * HH + n] = f2bf(hv);
            }
        }
        gbar(p.cnt, p.gen);
    }

    // ======== tail: out[:,149,:] from h150 (buffers 0) + hidden copy ========
    if (bid < 19) {
        const int n0 = bid * 32;
        const int row = wave * 16 + l15;
        f4v acc[2] = {};
        for (int kc = 0; kc < 16; ++kc) {
            const int kb = kc * 32 + lg * 8;
            s8v a = *(const s8v*)(p.hb0 + row * HH + kb);
#pragma unroll
            for (int q = 0; q < 2; ++q) {
                int n = n0 + q * 16 + l15;
                if (n >= VV) n = VV - 1;
                s8v b = *(const s8v*)(p.Wob + (size_t)n * HH + kb);
                acc[q] = __builtin_amdgcn_mfma_f32_16x16x32_bf16(a, b, acc[q], 0, 0, 0);
            }
        }
#pragma unroll
        for (int q = 0; q < 2; ++q) {
            const int n = n0 + q * 16 + l15;
            if (n < VV) {
                const float bias = p.bo[n];
#pragma unroll
                for (int i = 0; i < 4; ++i) {
                    const int m = wave * 16 + lg * 4 + i;
                    p.out[((size_t)m * TT + (TT - 1)) * VV + n] = acc[q][i] + bias;
                }
            }
        }
    } else if (bid < 51) {
        const int cb = bid - 19;
        const int i = cb * 2048 + tid * 4;
        float4 v = *(const float4*)(p.hf0 + i);
        *(float4*)(p.out + (size_t)BB * TT * VV + i) = v;
    }
}

// ------------------------------- host -------------------------------
extern "C" void kernel_launch(void* const* d_in, const int* in_sizes, int n_in,
                              void* d_out, int out_size, void* d_ws, size_t ws_size,
                              hipStream_t stream)
{
    const float* enc    = (const float*)d_in[0];
    const float* hidden = (const float*)d_in[1];
    const float* tseq   = (const float*)d_in[2];
    const float* Wa  = (const float*)d_in[4];
    const float* ba  = (const float*)d_in[5];
    const float* Wc  = (const float*)d_in[6];
    const float* bc  = (const float*)d_in[7];
    const float* Wih = (const float*)d_in[8];
    const float* Whh = (const float*)d_in[9];
    const float* bih = (const float*)d_in[10];
    const float* bhh = (const float*)d_in[11];
    const float* bo_ = (const float*)d_in[13];
    const float* Wo  = (const float*)d_in[12];
    float* out = (float*)d_out;

    char* w = (char*)d_ws;
    size_t off = 0;
    auto alloc = [&](size_t bytes) {
        void* q = w + off;
        off += (bytes + 255) & ~(size_t)255;
        return q;
    };
    int*    bar    = (int*)alloc(256);            // cnt @0, gen @128
    float*  lp0    = (float*)alloc((size_t)BB * SS * 4);
    float*  lp1    = (float*)alloc((size_t)BB * SS * 4);
    float*  ghb    = (float*)alloc((size_t)BB * G3 * 4);
    float*  part   = (float*)alloc((size_t)2 * BB * AA * 4);
    float*  h_f0   = (float*)alloc((size_t)BB * HH * 4);
    float*  h_f1   = (float*)alloc((size_t)BB * HH * 4);
    ushort* h_b0   = (ushort*)alloc((size_t)BB * HH * 2);
    ushort* h_b1   = (ushort*)alloc((size_t)BB * HH * 2);
    ushort* gruin  = (ushort*)alloc((size_t)BB * HH * 2);
    ushort* tseqb  = (ushort*)alloc((size_t)BB * TT * VV * 2);
    ushort* Wab    = (ushort*)alloc((size_t)SS * KCAT * 2);
    ushort* Wcb    = (ushort*)alloc((size_t)HH * KCAT * 2);
    ushort* Wihb   = (ushort*)alloc((size_t)G3 * HH * 2);
    ushort* Whhb   = (ushort*)alloc((size_t)G3 * HH * 2);
    ushort* Wob    = (ushort*)alloc((size_t)VV * HH * 2);
    const size_t enc_elems = (size_t)BB * SS * AA;
    const bool encbf = (off + enc_elems * 2) <= ws_size;
    ushort* encb = encbf ? (ushort*)alloc(enc_elems * 2) : nullptr;

    hipMemsetAsync(bar, 0, 256, stream);

    auto cvt = [&](const float* s, ushort* d, long n) {
        long n4 = n / 4;
        int blocks = (int)((n4 + 255) / 256);
        if (blocks > 4096) blocks = 4096;
        k_cvt4<<<blocks, 256, 0, stream>>>((const float4*)s, d, n4);
    };
    cvt(tseq, tseqb, (long)BB * TT * VV);
    cvt(Wa,  Wab,  (long)SS * KCAT);
    cvt(Wc,  Wcb,  (long)HH * KCAT);
    cvt(Wih, Wihb, (long)G3 * HH);
    cvt(Whh, Whhb, (long)G3 * HH);
    cvt(Wo,  Wob,  (long)VV * HH);
    if (encbf) cvt(enc, encb, (long)enc_elems);

    k_init_h<<<256, 256, 0, stream>>>(hidden, h_f0, h_b0);

    Prm prm;
    prm.tseqb = tseqb; prm.encb = encb; prm.encf = enc;
    prm.Wab = Wab; prm.Wcb = Wcb; prm.Wihb = Wihb; prm.Whhb = Whhb; prm.Wob = Wob;
    prm.ba = ba; prm.bc = bc; prm.bih = bih; prm.bhh = bhh; prm.bo = bo_;
    prm.lp0 = lp0; prm.lp1 = lp1; prm.ghb = ghb; prm.part = part;
    prm.hf0 = h_f0; prm.hf1 = h_f1; prm.hb0 = h_b0; prm.hb1 = h_b1;
    prm.gruin = gruin; prm.out = out;
    prm.cnt = bar; prm.gen = bar + 32;   // separate cache lines

    void* args[] = {&prm};
    if (encbf)
        hipLaunchCooperativeKernel((void*)kper<1>, dim3(NB), dim3(TPB), args, 0, stream);
    else
        hipLaunchCooperativeKernel((void*)kper<0>, dim3(NB), dim3(TPB), args, 0, stream);
}

// Round 3
// 20120.908 us; speedup vs baseline: 3.0456x; 3.0456x over previous
//
#include <hip/hip_runtime.h>
#include <stdint.h>

#define BB 128      // batch
#define TT 150      // seq len
#define HH 512      // hidden
#define AA 512      // attention dim
#define SS 1024     // 2A (softmax length)
#define VV 600      // vocab / output size
#define KCAT 1112   // V + H
#define G3 1536     // 3H
#define NB 256      // persistent grid (1 block/CU, co-resident)
#define TPB 512     // 8 waves

typedef short s8v __attribute__((ext_vector_type(8)));   // 8 x bf16
typedef float f4v __attribute__((ext_vector_type(4)));   // 4 x f32 acc

__device__ __forceinline__ ushort f2bf(float f) {
    uint32_t u = __builtin_bit_cast(uint32_t, f);
    uint32_t r = (u + 0x7fffu + ((u >> 16) & 1u)) >> 16;  // RNE
    return (ushort)r;
}
__device__ __forceinline__ float bflo(uint32_t x) {
    uint32_t u = (x & 0xffffu) << 16;
    return __builtin_bit_cast(float, u);
}
__device__ __forceinline__ float bfhi(uint32_t x) {
    uint32_t u = x & 0xffff0000u;
    return __builtin_bit_cast(float, u);
}

// ---------------- conversion: fp32 -> bf16 ----------------
__global__ void k_cvt4(const float4* __restrict__ src, ushort* __restrict__ dst, long n4) {
    long i = (long)blockIdx.x * blockDim.x + threadIdx.x;
    long st = (long)gridDim.x * blockDim.x;
    for (; i < n4; i += st) {
        float4 v = src[i];
        ushort4 o;
        o.x = f2bf(v.x); o.y = f2bf(v.y); o.z = f2bf(v.z); o.w = f2bf(v.w);
        *(ushort4*)(dst + i * 4) = o;
    }
}

__global__ void k_init_h(const float* __restrict__ hidden, float* __restrict__ hf,
                         ushort* __restrict__ hb) {
    int i = blockIdx.x * 256 + threadIdx.x;   // grid 256 -> 65536
    float v = hidden[i];
    hf[i] = v;
    hb[i] = f2bf(v);
}

struct Prm {
    const ushort* tseqb; const ushort* encb; const float* encf;
    const ushort *Wab, *Wcb, *Wihb, *Whhb, *Wob;
    const float *ba, *bc, *bih, *bhh, *bo;
    float *lp0, *lp1, *ghb, *part;
    float *hf0, *hf1; ushort *hb0, *hb1; ushort *gruin;
    float *out;
    int *cnt; int *gen;
};

// Grid barrier, storm-free version:
//  - arrival: one RELAXED agent fetch_add per block (monotonic, never reset)
//  - spin: RELAXED agent loads + s_sleep backoff -> NO cache ops in the loop
//  - visibility: exactly one __threadfence() (wb) before arrival and one
//    (inv) after release, per block per barrier.
__device__ __forceinline__ void gbar(int* cnt, int* gen, int& nbar) {
    __syncthreads();
    if (threadIdx.x == 0) {
        const int target = ++nbar;
        __threadfence();   // release: drain this block's writes to coherent point
        int v = __hip_atomic_fetch_add(cnt, 1, __ATOMIC_RELAXED, __HIP_MEMORY_SCOPE_AGENT);
        if (v == target * NB - 1) {
            __hip_atomic_store(gen, target, __ATOMIC_RELAXED, __HIP_MEMORY_SCOPE_AGENT);
        } else {
            int it = 0;
            while (__hip_atomic_load(gen, __ATOMIC_RELAXED, __HIP_MEMORY_SCOPE_AGENT) < target) {
                __builtin_amdgcn_s_sleep(32);              // ~0.85 us backoff
                if (++it > (1 << 21)) break;               // safety valve
            }
        }
        __threadfence();   // acquire: invalidate stale L1/L2 before next phase
    }
    __syncthreads();
}

__device__ __forceinline__ s8v ldA(const ushort* tseqb, const ushort* hb,
                                   int row, int kb, int t) {
    const s8v zf = {0, 0, 0, 0, 0, 0, 0, 0};
    if (kb >= KCAT) return zf;
    if (kb < VV) {
        if (t == 0) return zf;
        return *(const s8v*)(tseqb + ((size_t)row * TT + (t - 1)) * VV + kb);
    }
    return *(const s8v*)(hb + row * HH + (kb - VV));
}

template <int EBF>
__global__ __launch_bounds__(TPB, 2) void kper(Prm p) {
    const int bid = blockIdx.x;
    const int tid = threadIdx.x;
    const int wave = tid >> 6, lane = tid & 63;
    const int l15 = lane & 15, lg = lane >> 4;
    const s8v zf = {0, 0, 0, 0, 0, 0, 0, 0};
    int nbar = 0;
    __shared__ float aw[SS];
    __shared__ float red[TPB];
    __shared__ float redc[8][AA];

    for (int t = 0; t < TT; ++t) {
        const float*  hfc = (t & 1) ? p.hf1 : p.hf0;
        const ushort* hbc = (t & 1) ? p.hb1 : p.hb0;
        float*  hfn = (t & 1) ? p.hf0 : p.hf1;
        ushort* hbn = (t & 1) ? p.hb0 : p.hb1;

        // ======== phase A: logits split-K + gh + out[t-1] ========
        if (bid < 64) {
            const int ks = bid & 1, nt = bid >> 1;
            const int n0 = nt * 32;
            const int row = wave * 16 + l15;
            const int kc0 = ks ? 18 : 0, kc1 = ks ? 35 : 18;
            f4v acc[2] = {};
            for (int kc = kc0; kc < kc1; ++kc) {
                const int kb = kc * 32 + lg * 8;
                s8v a = ldA(p.tseqb, hbc, row, kb, t);
#pragma unroll
                for (int q = 0; q < 2; ++q) {
                    const int n = n0 + q * 16 + l15;
                    s8v b = (kb < KCAT) ? *(const s8v*)(p.Wab + (size_t)n * KCAT + kb) : zf;
                    acc[q] = __builtin_amdgcn_mfma_f32_16x16x32_bf16(a, b, acc[q], 0, 0, 0);
                }
            }
            float* lp = ks ? p.lp1 : p.lp0;
#pragma unroll
            for (int q = 0; q < 2; ++q) {
                const int n = n0 + q * 16 + l15;
#pragma unroll
                for (int i = 0; i < 4; ++i) {
                    const int m = wave * 16 + lg * 4 + i;
                    lp[m * SS + n] = acc[q][i];
                }
            }
        } else if (bid < 112) {
            const int jt = bid - 64;
            const int n0 = jt * 32;
            const int row = wave * 16 + l15;
            f4v acc[2] = {};
            for (int kc = 0; kc < 16; ++kc) {
                const int kb = kc * 32 + lg * 8;
                s8v a = *(const s8v*)(hbc + row * HH + kb);
#pragma unroll
                for (int q = 0; q < 2; ++q) {
                    const int n = n0 + q * 16 + l15;
                    s8v b = *(const s8v*)(p.Whhb + (size_t)n * HH + kb);
                    acc[q] = __builtin_amdgcn_mfma_f32_16x16x32_bf16(a, b, acc[q], 0, 0, 0);
                }
            }
#pragma unroll
            for (int q = 0; q < 2; ++q) {
                const int n = n0 + q * 16 + l15;
                const float bias = p.bhh[n];
#pragma unroll
                for (int i = 0; i < 4; ++i) {
                    const int m = wave * 16 + lg * 4 + i;
                    p.ghb[m * G3 + n] = acc[q][i] + bias;
                }
            }
        } else if (bid < 131 && t > 0) {
            const int nt = bid - 112;           // 0..18
            const int n0 = nt * 32;
            const int row = wave * 16 + l15;
            f4v acc[2] = {};
            for (int kc = 0; kc < 16; ++kc) {
                const int kb = kc * 32 + lg * 8;
                s8v a = *(const s8v*)(hbc + row * HH + kb);
#pragma unroll
                for (int q = 0; q < 2; ++q) {
                    int n = n0 + q * 16 + l15;
                    if (n >= VV) n = VV - 1;      // clamp load, mask store
                    s8v b = *(const s8v*)(p.Wob + (size_t)n * HH + kb);
                    acc[q] = __builtin_amdgcn_mfma_f32_16x16x32_bf16(a, b, acc[q], 0, 0, 0);
                }
            }
#pragma unroll
            for (int q = 0; q < 2; ++q) {
                const int n = n0 + q * 16 + l15;
                if (n < VV) {
                    const float bias = p.bo[n];
#pragma unroll
                    for (int i = 0; i < 4; ++i) {
                        const int m = wave * 16 + lg * 4 + i;
                        p.out[((size_t)m * TT + (t - 1)) * VV + n] = acc[q][i] + bias;
                    }
                }
            }
        }
        gbar(p.cnt, p.gen, nbar);

        // ======== phase B: softmax (redundant stats) + attention half-row ========
        {
            const int b = bid >> 1, half = bid & 1;
            const int s0 = tid * 2;
            float l0 = p.lp0[b * SS + s0]     + p.lp1[b * SS + s0]     + p.ba[s0];
            float l1 = p.lp0[b * SS + s0 + 1] + p.lp1[b * SS + s0 + 1] + p.ba[s0 + 1];
            red[tid] = fmaxf(l0, l1);
            __syncthreads();
            for (int s = TPB / 2; s > 0; s >>= 1) {
                if (tid < s) red[tid] = fmaxf(red[tid], red[tid + s]);
                __syncthreads();
            }
            const float mx = red[0];
            __syncthreads();
            float e0 = __expf(l0 - mx), e1 = __expf(l1 - mx);
            aw[s0] = e0; aw[s0 + 1] = e1;
            red[tid] = e0 + e1;
            __syncthreads();
            for (int s = TPB / 2; s > 0; s >>= 1) {
                if (tid < s) red[tid] += red[tid + s];
                __syncthreads();
            }
            const float inv = 1.0f / red[0];
            __syncthreads();

            float acc[8] = {0, 0, 0, 0, 0, 0, 0, 0};
            const int c0 = lane * 8;
#pragma unroll 4
            for (int it = 0; it < 64; ++it) {
                const int s = half * 512 + it * 8 + wave;
                const float w = aw[s];
                if (EBF) {
                    uint4 u = *(const uint4*)((const ushort*)p.encb + ((size_t)b * SS + s) * AA + c0);
                    acc[0] += w * bflo(u.x); acc[1] += w * bfhi(u.x);
                    acc[2] += w * bflo(u.y); acc[3] += w * bfhi(u.y);
                    acc[4] += w * bflo(u.z); acc[5] += w * bfhi(u.z);
                    acc[6] += w * bflo(u.w); acc[7] += w * bfhi(u.w);
                } else {
                    const float* rp = p.encf + ((size_t)b * SS + s) * AA + c0;
                    float4 v0 = *(const float4*)rp;
                    float4 v1 = *(const float4*)(rp + 4);
                    acc[0] += w * v0.x; acc[1] += w * v0.y;
                    acc[2] += w * v0.z; acc[3] += w * v0.w;
                    acc[4] += w * v1.x; acc[5] += w * v1.y;
                    acc[6] += w * v1.z; acc[7] += w * v1.w;
                }
            }
#pragma unroll
            for (int j = 0; j < 8; ++j) redc[wave][c0 + j] = acc[j];
            __syncthreads();
            {
                const int c = tid;  // 512 threads cover AA=512
                float s = ((redc[0][c] + redc[1][c]) + (redc[2][c] + redc[3][c]))
                        + ((redc[4][c] + redc[5][c]) + (redc[6][c] + redc[7][c]));
                p.part[((size_t)half * BB + b) * AA + c] = s * inv;
            }
        }
        gbar(p.cnt, p.gen, nbar);

        // ======== phase C: gru_in ========
        if (bid < 16) {
            const int n0 = bid * 32;
            const int row = wave * 16 + l15;
            f4v acc[2] = {};
            for (int kc = 0; kc < 35; ++kc) {
                const int kb = kc * 32 + lg * 8;
                s8v a;
                if (kb >= KCAT) a = zf;
                else if (kb < VV) {
                    a = (t == 0) ? zf
                        : *(const s8v*)(p.tseqb + ((size_t)row * TT + (t - 1)) * VV + kb);
                } else {
                    const int ko = kb - VV;
                    const float* q0 = p.part + ((size_t)0 * BB + row) * AA + ko;
                    const float* q1 = p.part + ((size_t)1 * BB + row) * AA + ko;
                    float4 x0 = *(const float4*)q0, y0 = *(const float4*)(q0 + 4);
                    float4 x1 = *(const float4*)q1, y1 = *(const float4*)(q1 + 4);
                    union { s8v v; ushort u[8]; } tu;
                    tu.u[0] = f2bf(x0.x + x1.x); tu.u[1] = f2bf(x0.y + x1.y);
                    tu.u[2] = f2bf(x0.z + x1.z); tu.u[3] = f2bf(x0.w + x1.w);
                    tu.u[4] = f2bf(y0.x + y1.x); tu.u[5] = f2bf(y0.y + y1.y);
                    tu.u[6] = f2bf(y0.z + y1.z); tu.u[7] = f2bf(y0.w + y1.w);
                    a = tu.v;
                }
#pragma unroll
                for (int q = 0; q < 2; ++q) {
                    const int n = n0 + q * 16 + l15;
                    s8v b = (kb < KCAT) ? *(const s8v*)(p.Wcb + (size_t)n * KCAT + kb) : zf;
                    acc[q] = __builtin_amdgcn_mfma_f32_16x16x32_bf16(a, b, acc[q], 0, 0, 0);
                }
            }
#pragma unroll
            for (int q = 0; q < 2; ++q) {
                const int n = n0 + q * 16 + l15;
                const float bias = p.bc[n];
#pragma unroll
                for (int i = 0; i < 4; ++i) {
                    const int m = wave * 16 + lg * 4 + i;
                    float v = acc[q][i] + bias;
                    p.gruin[m * HH + n] = f2bf(v > 0.0f ? v : 0.0f);
                }
            }
        }
        gbar(p.cnt, p.gen, nbar);

        // ======== phase D: gi + gates + h_new ========
        if (bid < 32) {
            const int j0 = bid * 16;
            const int row = wave * 16 + l15;
            const int n = j0 + l15;
            f4v ar = {}, az = {}, an = {};
            for (int kc = 0; kc < 16; ++kc) {
                const int kb = kc * 32 + lg * 8;
                s8v a  = *(const s8v*)(p.gruin + row * HH + kb);
                s8v br = *(const s8v*)(p.Wihb + (size_t)n * HH + kb);
                s8v bz = *(const s8v*)(p.Wihb + (size_t)(HH + n) * HH + kb);
                s8v bn = *(const s8v*)(p.Wihb + (size_t)(2 * HH + n) * HH + kb);
                ar = __builtin_amdgcn_mfma_f32_16x16x32_bf16(a, br, ar, 0, 0, 0);
                az = __builtin_amdgcn_mfma_f32_16x16x32_bf16(a, bz, az, 0, 0, 0);
                an = __builtin_amdgcn_mfma_f32_16x16x32_bf16(a, bn, an, 0, 0, 0);
            }
            const float br_ = p.bih[n], bz_ = p.bih[HH + n], bn_ = p.bih[2 * HH + n];
#pragma unroll
            for (int i = 0; i < 4; ++i) {
                const int m = wave * 16 + lg * 4 + i;
                const float* ghm = p.ghb + (size_t)m * G3;
                float gr = ar[i] + br_ + ghm[n];
                float gz = az[i] + bz_ + ghm[HH + n];
                float r = 1.0f / (1.0f + __expf(-gr));
                float z = 1.0f / (1.0f + __expf(-gz));
                float nn = tanhf(an[i] + bn_ + r * ghm[2 * HH + n]);
                float hold = hfc[m * HH + n];
                float hv = (1.0f - z) * nn + z * hold;
                hfn[m * HH + n] = hv;
                hbn[m * HH + n] = f2bf(hv);
            }
        }
        gbar(p.cnt, p.gen, nbar);
    }

    // ======== tail: out[:,149,:] from h150 (buffers 0) + hidden copy ========
    if (bid < 19) {
        const int n0 = bid * 32;
        const int row = wave * 16 + l15;
        f4v acc[2] = {};
        for (int kc = 0; kc < 16; ++kc) {
            const int kb = kc * 32 + lg * 8;
            s8v a = *(const s8v*)(p.hb0 + row * HH + kb);
#pragma unroll
            for (int q = 0; q < 2; ++q) {
                int n = n0 + q * 16 + l15;
                if (n >= VV) n = VV - 1;
                s8v b = *(const s8v*)(p.Wob + (size_t)n * HH + kb);
                acc[q] = __builtin_amdgcn_mfma_f32_16x16x32_bf16(a, b, acc[q], 0, 0, 0);
            }
        }
#pragma unroll
        for (int q = 0; q < 2; ++q) {
            const int n = n0 + q * 16 + l15;
            if (n < VV) {
                const float bias = p.bo[n];
#pragma unroll
                for (int i = 0; i < 4; ++i) {
                    const int m = wave * 16 + lg * 4 + i;
                    p.out[((size_t)m * TT + (TT - 1)) * VV + n] = acc[q][i] + bias;
                }
            }
        }
    } else if (bid < 51) {
        const int cb = bid - 19;
        const int i = cb * 2048 + tid * 4;
        float4 v = *(const float4*)(p.hf0 + i);
        *(float4*)(p.out + (size_t)BB * TT * VV + i) = v;
    }
}

// ------------------------------- host -------------------------------
extern "C" void kernel_launch(void* const* d_in, const int* in_sizes, int n_in,
                              void* d_out, int out_size, void* d_ws, size_t ws_size,
                              hipStream_t stream)
{
    const float* enc    = (const float*)d_in[0];
    const float* hidden = (const float*)d_in[1];
    const float* tseq   = (const float*)d_in[2];
    const float* Wa  = (const float*)d_in[4];
    const float* ba  = (const float*)d_in[5];
    const float* Wc  = (const float*)d_in[6];
    const float* bc  = (const float*)d_in[7];
    const float* Wih = (const float*)d_in[8];
    const float* Whh = (const float*)d_in[9];
    const float* bih = (const float*)d_in[10];
    const float* bhh = (const float*)d_in[11];
    const float* Wo  = (const float*)d_in[12];
    const float* bo_ = (const float*)d_in[13];
    float* out = (float*)d_out;

    char* w = (char*)d_ws;
    size_t off = 0;
    auto alloc = [&](size_t bytes) {
        void* q = w + off;
        off += (bytes + 255) & ~(size_t)255;
        return q;
    };
    int*    bar    = (int*)alloc(256);            // cnt @0, gen @128
    float*  lp0    = (float*)alloc((size_t)BB * SS * 4);
    float*  lp1    = (float*)alloc((size_t)BB * SS * 4);
    float*  ghb    = (float*)alloc((size_t)BB * G3 * 4);
    float*  part   = (float*)alloc((size_t)2 * BB * AA * 4);
    float*  h_f0   = (float*)alloc((size_t)BB * HH * 4);
    float*  h_f1   = (float*)alloc((size_t)BB * HH * 4);
    ushort* h_b0   = (ushort*)alloc((size_t)BB * HH * 2);
    ushort* h_b1   = (ushort*)alloc((size_t)BB * HH * 2);
    ushort* gruin  = (ushort*)alloc((size_t)BB * HH * 2);
    ushort* tseqb  = (ushort*)alloc((size_t)BB * TT * VV * 2);
    ushort* Wab    = (ushort*)alloc((size_t)SS * KCAT * 2);
    ushort* Wcb    = (ushort*)alloc((size_t)HH * KCAT * 2);
    ushort* Wihb   = (ushort*)alloc((size_t)G3 * HH * 2);
    ushort* Whhb   = (ushort*)alloc((size_t)G3 * HH * 2);
    ushort* Wob    = (ushort*)alloc((size_t)VV * HH * 2);
    const size_t enc_elems = (size_t)BB * SS * AA;
    const bool encbf = (off + enc_elems * 2) <= ws_size;
    ushort* encb = encbf ? (ushort*)alloc(enc_elems * 2) : nullptr;

    hipMemsetAsync(bar, 0, 256, stream);

    auto cvt = [&](const float* s, ushort* d, long n) {
        long n4 = n / 4;
        int blocks = (int)((n4 + 255) / 256);
        if (blocks > 4096) blocks = 4096;
        k_cvt4<<<blocks, 256, 0, stream>>>((const float4*)s, d, n4);
    };
    cvt(tseq, tseqb, (long)BB * TT * VV);
    cvt(Wa,  Wab,  (long)SS * KCAT);
    cvt(Wc,  Wcb,  (long)HH * KCAT);
    cvt(Wih, Wihb, (long)G3 * HH);
    cvt(Whh, Whhb, (long)G3 * HH);
    cvt(Wo,  Wob,  (long)VV * HH);
    if (encbf) cvt(enc, encb, (long)enc_elems);

    k_init_h<<<256, 256, 0, stream>>>(hidden, h_f0, h_b0);

    Prm prm;
    prm.tseqb = tseqb; prm.encb = encb; prm.encf = enc;
    prm.Wab = Wab; prm.Wcb = Wcb; prm.Wihb = Wihb; prm.Whhb = Whhb; prm.Wob = Wob;
    prm.ba = ba; prm.bc = bc; prm.bih = bih; prm.bhh = bhh; prm.bo = bo_;
    prm.lp0 = lp0; prm.lp1 = lp1; prm.ghb = ghb; prm.part = part;
    prm.hf0 = h_f0; prm.hf1 = h_f1; prm.hb0 = h_b0; prm.hb1 = h_b1;
    prm.gruin = gruin; prm.out = out;
    prm.cnt = bar; prm.gen = bar + 32;   // separate cache lines

    void* args[] = {&prm};
    if (encbf)
        hipLaunchCooperativeKernel((void*)kper<1>, dim3(NB), dim3(TPB), args, 0, stream);
    else
        hipLaunchCooperativeKernel((void*)kper<0>, dim3(NB), dim3(TPB), args, 0, stream);
}